// Round 1
// baseline (192.094 us; speedup 1.0000x reference)
//
#include <hip/hip_runtime.h>
#include <math.h>

#define NN 200000
#define H 128
#define HID 512

// workspace layout: 8-byte aligned best first
struct Ws {
    unsigned long long best;   // packed (fkey(score)<<32) | (0xFFFFFFFF - idx)
    float Z;                   // sum of exp(attn)
    float s_b;                 // phi1 . b2
    float u[H];                // W2^T phi1
};

__device__ __forceinline__ unsigned int fkey(float f) {
    unsigned int u = __float_as_uint(f);
    return (u & 0x80000000u) ? ~u : (u | 0x80000000u);
}
__device__ __forceinline__ float inv_fkey(unsigned int k) {
    return __uint_as_float((k & 0x80000000u) ? (k ^ 0x80000000u) : ~k);
}

// ---------------- prep: phi1 = W1*v_i + b1 ; u = W2^T phi1 ; s_b = phi1.b2 ----
// grid = 32 blocks x 256 threads, 16 k-rows per block
__global__ __launch_bounds__(256)
void prep_kernel(const float* __restrict__ outp, const float* __restrict__ W1,
                 const float* __restrict__ b1, const float* __restrict__ W2,
                 const float* __restrict__ b2, const int* __restrict__ prev,
                 Ws* __restrict__ ws) {
    __shared__ float phi1_s[16];
    __shared__ float sb_s[16];
    __shared__ float u_s[256];
    int t = threadIdx.x;
    int lane = t & 63;
    int c = lane & 31;          // float4 column within a row
    int hw = t >> 5;            // half-wave id 0..7
    const float* vi = outp + (size_t)prev[0] * H;
    float4 v = ((const float4*)vi)[c];
#pragma unroll
    for (int r = 0; r < 2; ++r) {
        int kl = hw + r * 8;                 // 0..15
        int k = blockIdx.x * 16 + kl;
        float4 w = ((const float4*)(W1 + (size_t)k * H))[c];
        float d = w.x * v.x + w.y * v.y + w.z * v.z + w.w * v.w;
        d += __shfl_xor(d, 16);
        d += __shfl_xor(d, 8);
        d += __shfl_xor(d, 4);
        d += __shfl_xor(d, 2);
        d += __shfl_xor(d, 1);
        if (c == 0) {
            float phi = d + b1[k];
            phi1_s[kl] = phi;
            sb_s[kl] = phi * b2[k];
        }
    }
    __syncthreads();
    if (t == 0) {
        float s = 0.f;
#pragma unroll
        for (int i = 0; i < 16; ++i) s += sb_s[i];
        atomicAdd(&ws->s_b, s);
    }
    // u partials: thread t handles column h = t&127, k-subset g = t>>7
    int h = t & 127;
    int g = t >> 7;   // 0 or 1
    float up = 0.f;
#pragma unroll
    for (int kk = 0; kk < 8; ++kk) {
        int kl = g * 8 + kk;
        int k = blockIdx.x * 16 + kl;
        up += phi1_s[kl] * W2[(size_t)k * H + h];
    }
    u_s[t] = up;
    __syncthreads();
    if (t < 128) atomicAdd(&ws->u[h], u_s[t] + u_s[t + 128]);
}

// ---------------- main streaming pass -----------------------------------------
// Each half-wave (32 lanes) owns one row per iteration: 32 x float4 = 512 B.
// A full wave reads a contiguous, aligned 1 KB (rows 2p, 2p+1).
__global__ __launch_bounds__(256)
void score_kernel(const float4* __restrict__ xv, const float* __restrict__ adj,
                  Ws* __restrict__ ws, int n) {
    __shared__ float zs[8];
    __shared__ unsigned long long bs[8];
    const float inv = 0.04419417382415922f;   // 1/sqrt(512)
    int t = threadIdx.x;
    int lane = t & 63;
    int c = lane & 31;
    int half = lane >> 5;
    int wib = t >> 6;                 // wave in block 0..3
    int tlid = wib * 2 + half;        // tail slot 0..7
    float s_b = ws->s_b;
    float4 uv = ((const float4*)ws->u)[c];
    int gw = blockIdx.x * 4 + wib;
    int nw = gridDim.x * 4;
    int npairs = n >> 1;
    float zloc = 0.f;
    float bscore = -3.4e38f;
    int bidx = -1;
    for (int p = gw; p < npairs; p += nw) {
        int row = p * 2 + half;
        float4 x = xv[(size_t)row * 32 + c];
        float d = x.x * uv.x + x.y * uv.y + x.z * uv.z + x.w * uv.w;
        d += __shfl_xor(d, 16);
        d += __shfl_xor(d, 8);
        d += __shfl_xor(d, 4);
        d += __shfl_xor(d, 2);
        d += __shfl_xor(d, 1);
        if (c == 0) {
            float a = adj[row];
            float attn = 0.f;
            if (a != 0.f) {
                float score = (s_b + a * d) * inv;
                attn = 10.f * tanhf(score);
                if (score > bscore) { bscore = score; bidx = row; }
            }
            zloc += __expf(attn);
        }
    }
    if (c == 0) {
        zs[tlid] = zloc;
        unsigned long long pk = 0ull;
        if (bidx >= 0)
            pk = ((unsigned long long)fkey(bscore) << 32) |
                 (unsigned long long)(0xFFFFFFFFu - (unsigned int)bidx);
        bs[tlid] = pk;
    }
    __syncthreads();
    if (t == 0) {
        float z = 0.f;
        unsigned long long pk = 0ull;
#pragma unroll
        for (int i = 0; i < 8; ++i) { z += zs[i]; if (bs[i] > pk) pk = bs[i]; }
        atomicAdd(&ws->Z, z);
        atomicMax(&ws->best, pk);
    }
}

// ---------------- finalize ----------------------------------------------------
__global__ void final_kernel(const Ws* __restrict__ ws, float* __restrict__ outp) {
    unsigned long long b = ws->best;
    float Z = ws->Z;
    unsigned int idx = 0xFFFFFFFFu - (unsigned int)(b & 0xFFFFFFFFu);
    float score = inv_fkey((unsigned int)(b >> 32));
    float p = __expf(10.f * tanhf(score)) / Z;
    if (b == 0ull) { idx = 0; p = 0.f; }
    outp[0] = (float)idx;
    outp[1] = p;
}

extern "C" void kernel_launch(void* const* d_in, const int* in_sizes, int n_in,
                              void* d_out, int out_size, void* d_ws, size_t ws_size,
                              hipStream_t stream) {
    const float* outp = (const float*)d_in[0];
    const float* adj  = (const float*)d_in[1];
    const float* W1   = (const float*)d_in[2];
    const float* b1   = (const float*)d_in[3];
    const float* W2   = (const float*)d_in[4];
    const float* b2   = (const float*)d_in[5];
    const int*   prev = (const int*)d_in[6];
    int n = in_sizes[1];                       // N = 200000
    Ws* ws = (Ws*)d_ws;

    hipMemsetAsync(ws, 0, sizeof(Ws), stream);
    prep_kernel<<<32, 256, 0, stream>>>(outp, W1, b1, W2, b2, prev, ws);
    score_kernel<<<1024, 256, 0, stream>>>((const float4*)outp, adj, ws, n);
    final_kernel<<<1, 1, 0, stream>>>(ws, (float*)d_out);
}